// Round 2
// baseline (392.125 us; speedup 1.0000x reference)
//
#include <hip/hip_runtime.h>

// CustomQuantizer: idx = argmax(x, axis=-1); out[n, :] = W[:, idx[n]] = W.T[idx[n], :]
//   x: [N_TOKENS, QUANT_DIM] fp32   (8192 x 8192)
//   W: [OUT_DIM, QUANT_DIM]  fp32   (1024 x 8192)
//   out: [N_TOKENS, OUT_DIM] fp32   (8192 x 1024)
//
// R1 lesson: direct column gather = strided 32KB scatter, latency + line-refill bound.
// R2 (transpose W -> WT in ws): correct but moves 64-96 MB of extra HBM traffic
//   (WT write + WT re-read) and serializes 3 phases.
// R3: W-stationary scatter. Kernel 1 writes idx[n] only (32 KB). Kernel 2
//   partitions W into [256-row x 32-col] slabs (one 128B line width per row ->
//   every fetched byte is used, read exactly once), stages slab in LDS, scans the
//   L2-resident idx array, and writes 1KB contiguous out-row segments per match.
//   Algorithmic HBM floor: 256 MB (x) + 32 MB (W) + 32 MB (out) = 320 MB.
// R4 (this): R3 bench died to container infra failure (no counters). Source audit
//   found no OOB/barrier/capture hazard; resubmitting with a defensive clamp on
//   the LDS match-list slot (the only write whose bound is by-construction).

#define QUANT_DIM 8192
#define OUT_DIM   1024
#define BLOCK     256
#define CCOLS     32          // columns per chunk = 128 B line width
#define JROWS     256         // W rows staged per block
#define SEG       1024        // idx tokens scanned per segment (bounds LDS list)

// ---------------- kernel 1: per-row argmax -> idx ----------------
__global__ __launch_bounds__(BLOCK) void argmax_idx(
    const float* __restrict__ x, int* __restrict__ idx_out, int n_tokens)
{
    const int row = blockIdx.x;
    if (row >= n_tokens) return;
    const int tid = threadIdx.x;
    const float* xr = x + (size_t)row * QUANT_DIM;

    // local argmax; per-thread indices increase with i -> strict '>' keeps first
    float best = -INFINITY;
    int bidx = 0;
    #pragma unroll
    for (int i = 0; i < QUANT_DIM / (BLOCK * 4); ++i) {
        const int base = i * (BLOCK * 4) + tid * 4;
        const float4 v = *reinterpret_cast<const float4*>(xr + base);
        if (v.x > best) { best = v.x; bidx = base;     }
        if (v.y > best) { best = v.y; bidx = base + 1; }
        if (v.z > best) { best = v.z; bidx = base + 2; }
        if (v.w > best) { best = v.w; bidx = base + 3; }
    }

    // wave (64-lane) reduction, tie-break to smaller index
    #pragma unroll
    for (int off = 32; off > 0; off >>= 1) {
        const float ov = __shfl_down(best, off, 64);
        const int   oi = __shfl_down(bidx, off, 64);
        if (ov > best || (ov == best && oi < bidx)) { best = ov; bidx = oi; }
    }

    __shared__ float sval[BLOCK / 64];
    __shared__ int   sidx[BLOCK / 64];
    const int wave = tid >> 6;
    if ((tid & 63) == 0) { sval[wave] = best; sidx[wave] = bidx; }
    __syncthreads();
    if (tid == 0) {
        float b = sval[0];
        int   bi = sidx[0];
        #pragma unroll
        for (int w = 1; w < BLOCK / 64; ++w) {
            if (sval[w] > b || (sval[w] == b && sidx[w] < bi)) {
                b = sval[w]; bi = sidx[w];
            }
        }
        idx_out[row] = bi;
    }
}

// ---------------- kernel 2: W-stationary scatter ----------------
// grid = (QUANT_DIM/CCOLS) * (OUT_DIM/JROWS) = 256 * 4 = 1024 blocks.
// Block (chunk, jq): stages W[j0:j0+256][c0:c0+32] (32 KB, coalesced full lines),
// scans idx in SEG-sized segments, and for each token n with idx[n] in
// [c0, c0+32) writes out[n][j0:j0+256] = tile[:, idx[n]-c0] as one block-wide
// 1 KB coalesced store.
__global__ __launch_bounds__(BLOCK) void scatter_w(
    const float* __restrict__ W,
    const int*   __restrict__ idx,
    float*       __restrict__ out,
    int n_tokens)
{
    const int jq    = blockIdx.x & (OUT_DIM / JROWS - 1);   // 0..3
    const int chunk = blockIdx.x >> 2;                       // 0..255
    const int c0 = chunk * CCOLS;
    const int j0 = jq * JROWS;
    const int tid = threadIdx.x;

    __shared__ float tile[JROWS][CCOLS + 1];   // +1 pad: (r+c)%32 banks, conflict-free
    __shared__ int   list[SEG];
    __shared__ int   nmatch;

    // stage slab: lane c in 0..31, rows r0 + 8k. Per wave: 2 rows x 128 B, full lines.
    const int c  = tid & 31;
    const int r0 = tid >> 5;                   // 0..7
    #pragma unroll
    for (int k = 0; k < JROWS / 8; ++k) {
        const int r = r0 + k * 8;
        tile[r][c] = W[(size_t)(j0 + r) * QUANT_DIM + c0 + c];
    }

    for (int seg = 0; seg < n_tokens; seg += SEG) {
        if (tid == 0) nmatch = 0;
        __syncthreads();                       // covers tile staging on first pass

        const int segn = (n_tokens - seg < SEG) ? (n_tokens - seg) : SEG;
        for (int t = tid; t < segn; t += BLOCK) {
            const int v  = idx[seg + t];       // 32 KB total, L2-resident
            const int cc = v - c0;
            if (cc >= 0 && cc < CCOLS) {
                const int slot = atomicAdd(&nmatch, 1);
                if (slot < SEG) list[slot] = ((seg + t) << 5) | cc;  // clamp: defensive
            }
        }
        __syncthreads();

        const int m = (nmatch < SEG) ? nmatch : SEG;
        for (int e = 0; e < m; ++e) {
            const int pk = list[e];
            const int n  = pk >> 5;
            const int cc = pk & 31;
            // LDS read tile[tid][cc]: bank (tid+cc)%32 -> 2 lanes/bank (free).
            // Store: 256 consecutive floats -> fully coalesced 1 KB.
            out[(size_t)n * OUT_DIM + j0 + tid] = tile[tid][cc];
        }
        __syncthreads();                       // protect list/nmatch before next seg
    }
}

// ---------------- fallback (ws too small for idx): direct column gather ----------------
__global__ __launch_bounds__(BLOCK) void quantizer_fused_direct(
    const float* __restrict__ x,
    const float* __restrict__ W,
    float* __restrict__ out,
    int n_tokens)
{
    const int row = blockIdx.x;
    if (row >= n_tokens) return;
    const int tid = threadIdx.x;
    const float* xr = x + (size_t)row * QUANT_DIM;

    float best = -INFINITY;
    int bidx = 0;
    #pragma unroll
    for (int i = 0; i < QUANT_DIM / (BLOCK * 4); ++i) {
        const int base = i * (BLOCK * 4) + tid * 4;
        const float4 v = *reinterpret_cast<const float4*>(xr + base);
        if (v.x > best) { best = v.x; bidx = base;     }
        if (v.y > best) { best = v.y; bidx = base + 1; }
        if (v.z > best) { best = v.z; bidx = base + 2; }
        if (v.w > best) { best = v.w; bidx = base + 3; }
    }
    #pragma unroll
    for (int off = 32; off > 0; off >>= 1) {
        const float ov = __shfl_down(best, off, 64);
        const int   oi = __shfl_down(bidx, off, 64);
        if (ov > best || (ov == best && oi < bidx)) { best = ov; bidx = oi; }
    }
    __shared__ float sval[BLOCK / 64];
    __shared__ int   sidx[BLOCK / 64];
    __shared__ int   result;
    const int wave = tid >> 6;
    if ((tid & 63) == 0) { sval[wave] = best; sidx[wave] = bidx; }
    __syncthreads();
    if (tid == 0) {
        float b = sval[0];
        int   bi = sidx[0];
        #pragma unroll
        for (int w = 1; w < BLOCK / 64; ++w) {
            if (sval[w] > b || (sval[w] == b && sidx[w] < bi)) {
                b = sval[w]; bi = sidx[w];
            }
        }
        result = bi;
    }
    __syncthreads();
    const int idx = result;
    float* orow = out + (size_t)row * OUT_DIM;
    for (int j = tid; j < OUT_DIM; j += BLOCK) {
        orow[j] = W[(size_t)j * QUANT_DIM + idx];
    }
}

extern "C" void kernel_launch(void* const* d_in, const int* in_sizes, int n_in,
                              void* d_out, int out_size, void* d_ws, size_t ws_size,
                              hipStream_t stream) {
    const float* x = (const float*)d_in[0];
    const float* W = (const float*)d_in[1];
    float* out = (float*)d_out;
    const int n_tokens = in_sizes[0] / QUANT_DIM;
    const size_t idx_bytes = (size_t)n_tokens * sizeof(int);

    if (ws_size >= idx_bytes) {
        int* idx = (int*)d_ws;
        argmax_idx<<<n_tokens, BLOCK, 0, stream>>>(x, idx, n_tokens);
        const int grid2 = (QUANT_DIM / CCOLS) * (OUT_DIM / JROWS);   // 1024
        scatter_w<<<grid2, BLOCK, 0, stream>>>(W, idx, out, n_tokens);
    } else {
        quantizer_fused_direct<<<n_tokens, BLOCK, 0, stream>>>(x, W, out, n_tokens);
    }
}